// Round 14
// baseline (296.489 us; speedup 1.0000x reference)
//
#include <hip/hip_runtime.h>

#define N_NODES 50000
#define HID 256
#define HEADS 8
#define HDIM 32
#define N_EDGES 800000

typedef __bf16 bf16x8 __attribute__((ext_vector_type(8)));
typedef float f32x4 __attribute__((ext_vector_type(4)));
typedef float f32x2 __attribute__((ext_vector_type(2)));

__device__ __forceinline__ unsigned short f2bf(float f) {
    unsigned int b = __float_as_uint(f);
    unsigned int r = (b + 0x7FFFu + ((b >> 16) & 1u)) >> 16;
    return (unsigned short)r;
}
__device__ __forceinline__ float bf2f(unsigned short u) {
    return __uint_as_float(((unsigned int)u) << 16);
}
__device__ __forceinline__ f32x2 bfpair(unsigned int u) {
    f32x2 r;
    r[0] = __uint_as_float(u << 16);
    r[1] = __uint_as_float(u & 0xffff0000u);
    return r;
}

// Fused column p in [0,1024):
//   p<256      : Q col p (bf16 out)
//   256<=p<768 : p'=p-256; quad=p'>>2, r=p'&3: r<2 -> K ch quad*2+r,
//                r>=2 -> V ch quad*2+(r-2); scaled x64 (fp8 out, kkvv quads)
//   p>=768     : skip col p-768 (bf16 out)
__device__ __forceinline__ void fused_col_map(int p, int& mat, int& col, float& scale) {
    if (p < 256) { mat = 0; col = p; scale = 1.0f; }
    else if (p < 768) {
        int pp = p - 256;
        mat = ((pp & 2) ? 2 : 1);
        col = ((pp >> 2) << 1) | (pp & 1);
        scale = 64.0f;
    } else { mat = 3; col = p - 768; scale = 1.0f; }
}

// ---------------- fused: x fp32->bf16 | degree hist | weight pack ----------------
__global__ __launch_bounds__(256) void prep_kernel(
    const float* __restrict__ x, unsigned short* __restrict__ xb,
    const int* __restrict__ dst, int* __restrict__ deg,
    const float* __restrict__ Wq, const float* __restrict__ Wk,
    const float* __restrict__ Wv, const float* __restrict__ Ws,
    const float* __restrict__ bq, const float* __restrict__ bk,
    const float* __restrict__ bv, const float* __restrict__ bs,
    unsigned short* __restrict__ wpack, float* __restrict__ biasF) {
    int b = blockIdx.x;
    if (b < 6250) {
        int t = b * 256 + threadIdx.x;
        const float4* p = reinterpret_cast<const float4*>(x) + (size_t)t * 2;
        float4 f0 = p[0], f1 = p[1];
        uint4 o;
        o.x = (unsigned)f2bf(f0.x) | ((unsigned)f2bf(f0.y) << 16);
        o.y = (unsigned)f2bf(f0.z) | ((unsigned)f2bf(f0.w) << 16);
        o.z = (unsigned)f2bf(f1.x) | ((unsigned)f2bf(f1.y) << 16);
        o.w = (unsigned)f2bf(f1.z) | ((unsigned)f2bf(f1.w) << 16);
        reinterpret_cast<uint4*>(xb)[t] = o;
    } else if (b < 9375) {
        int e = (b - 6250) * 256 + threadIdx.x;
        atomicAdd(&deg[dst[e]], 1);
    } else {
        int t = (b - 9375) * 256 + threadIdx.x;  // 262144 total
        int e = t & 7, lane = (t >> 3) & 63, kk = (t >> 9) & 7, n_tile = t >> 12;
        int k = kk * 32 + (lane >> 4) * 8 + e;
        int p = n_tile * 16 + (lane & 15);
        const float* W[4] = {Wq, Wk, Wv, Ws};
        int mat, col; float scale;
        fused_col_map(p, mat, col, scale);
        wpack[t] = f2bf(W[mat][k * 256 + col] * scale);
        if (t < 1024) {
            const float* B[4] = {bq, bk, bv, bs};
            int mat2, col2; float s2;
            fused_col_map(t, mat2, col2, s2);
            biasF[t] = B[mat2][col2] * s2;
        }
    }
}

// ---------------- CSR build: parallel scan ----------------
__global__ __launch_bounds__(1024) void scan1_kernel(
    const int* __restrict__ deg, int* __restrict__ row_ptr,
    int* __restrict__ btot, int n) {
    int tid = threadIdx.x, lane = tid & 63, wv = tid >> 6;
    int idx = blockIdx.x * 1024 + tid;
    int v = (idx < n) ? deg[idx] : 0;
    int inc = v;
#pragma unroll
    for (int off = 1; off < 64; off <<= 1) {
        int t2 = __shfl_up(inc, off);
        if (lane >= off) inc += t2;
    }
    __shared__ int sW[16], sO[16];
    if (lane == 63) sW[wv] = inc;
    __syncthreads();
    if (tid < 16) {
        int vv = sW[tid], in2 = vv;
        for (int off = 1; off < 16; off <<= 1) {
            int t2 = __shfl_up(in2, off);
            if (tid >= off) in2 += t2;
        }
        sO[tid] = in2 - vv;
    }
    __syncthreads();
    int excl = sO[wv] + inc - v;
    if (idx <= n) row_ptr[idx] = excl;  // provisional
    if (tid == 1023) btot[blockIdx.x] = excl + v;
}

// fixup with inline 50-entry second-level scan
__global__ __launch_bounds__(256) void fixup_kernel(
    int* __restrict__ row_ptr, int* __restrict__ fill,
    const int* __restrict__ btot, int n) {
    __shared__ int sB;
    int tid = threadIdx.x;
    if (tid < 64) {
        int v = (tid < 50) ? btot[tid] : 0;
        int inc = v;
#pragma unroll
        for (int off = 1; off < 64; off <<= 1) {
            int t2 = __shfl_up(inc, off);
            if (tid >= off) inc += t2;
        }
        if (tid == (blockIdx.x >> 2)) sB = inc - v;
    }
    __syncthreads();
    int idx = blockIdx.x * 256 + tid;
    if (idx > n) return;
    int v = row_ptr[idx] + sB;
    row_ptr[idx] = v;
    if (idx < n) fill[idx] = v;
}

// ---------------- fused QKVS GEMM (2 M-tiles/block) + INTERLEAVED scatter ----------
// Grid 6272: even bid -> GEMM block bid/2 (0..3135), odd -> scatter bid/2
// (active < 3125). 1:1 interleave keeps scatter co-resident with GEMM for
// the whole dispatch (R13-verified: tail placement serializes, -29us).
// GEMM block: 256 rows x 64 fused-cols, 4 waves; B slice (32 KB) LDS-staged
// once; per kk-step 4 A-loads feed 16 MFMA (2x the R13 MFMA/latency ratio).
__global__ __launch_bounds__(256) void gemm_scatter_kernel(
    const int* __restrict__ src, const int* __restrict__ dst,
    int* __restrict__ fill, unsigned short* __restrict__ csr_src,
    const unsigned short* __restrict__ xb,     // [N][256] bf16
    const unsigned short* __restrict__ wpack,  // packed W (512 KB)
    const float* __restrict__ biasF,           // [1024]
    unsigned short* __restrict__ qs,           // [N][256] bf16
    unsigned char* __restrict__ kv,            // [N][512] fp8
    unsigned short* __restrict__ sk,           // [N][256] bf16
    int n_nodes) {
    __shared__ __align__(16) uint4 bsh[2048];  // 32 KB B slice
    int bid = blockIdx.x;                      // 6272
    if (bid & 1) {
        int sid = bid >> 1;                    // scatter block, active < 3125
        int e = sid * 256 + threadIdx.x;
        if (sid < 3125 && e < N_EDGES) {
            int pos = atomicAdd(&fill[dst[e]], 1);
            csr_src[pos] = (unsigned short)src[e];
        }
        return;
    }
    int gid = bid >> 1;                        // 0..3135 = 8 * 392
    int work = (gid & 7) * 392 + (gid >> 3);   // XCD-chunked
    int mt = work >> 4;                        // 0..195 (196*256 = 50176 rows)
    int nt = work & 15;
    int lane = threadIdx.x & 63;
    int wv = threadIdx.x >> 6;
    int row_w = mt * 256 + wv * 32;
    int n0 = nt * 64;
    int ntile0 = n0 >> 4;

    // stage B slice: contiguous 2048 uint4 starting at ntile0*8*64
    {
        const uint4* bsrc = reinterpret_cast<const uint4*>(wpack) +
                            (size_t)ntile0 * 8 * 64;
        int tid = threadIdx.x;
#pragma unroll
        for (int i = 0; i < 8; ++i)
            bsh[i * 256 + tid] = bsrc[i * 256 + tid];
    }
    __syncthreads();

    f32x4 acc[4][4];
#pragma unroll
    for (int ms = 0; ms < 4; ++ms)
#pragma unroll
        for (int ni = 0; ni < 4; ++ni) {
            f32x4 z = {0.f, 0.f, 0.f, 0.f};
            acc[ms][ni] = z;
        }

    // row-frag ms: row_w + (ms&1)*16 + (ms>>1)*128
    int arow[4];
#pragma unroll
    for (int ms = 0; ms < 4; ++ms)
        arow[ms] = min(row_w + (ms & 1) * 16 + (ms >> 1) * 128 + (lane & 15),
                       n_nodes - 1);
    int acol = (lane >> 4) * 8;

#pragma unroll
    for (int kk = 0; kk < 8; ++kk) {
        bf16x8 a[4], bfr[4];
#pragma unroll
        for (int ms = 0; ms < 4; ++ms) {
            uint4 u = *reinterpret_cast<const uint4*>(
                xb + (size_t)arow[ms] * 256 + kk * 32 + acol);
            a[ms] = __builtin_bit_cast(bf16x8, u);
        }
#pragma unroll
        for (int ni = 0; ni < 4; ++ni) {
            uint4 u = bsh[(ni * 8 + kk) * 64 + lane];
            bfr[ni] = __builtin_bit_cast(bf16x8, u);
        }
#pragma unroll
        for (int ms = 0; ms < 4; ++ms)
#pragma unroll
            for (int ni = 0; ni < 4; ++ni)
                acc[ms][ni] = __builtin_amdgcn_mfma_f32_16x16x32_bf16(
                    a[ms], bfr[ni], acc[ms][ni], 0, 0, 0);
    }

    // epilogue: col = n0+ni*16+(lane&15), row = base_ms+(lane>>4)*4+r
    int region = (n0 < 256) ? 0 : (n0 < 768 ? 1 : 2);
#pragma unroll
    for (int ms = 0; ms < 4; ++ms) {
        int rbase = row_w + (ms & 1) * 16 + (ms >> 1) * 128 + (lane >> 4) * 4;
#pragma unroll
        for (int ni = 0; ni < 4; ++ni) {
            int col = n0 + ni * 16 + (lane & 15);
            float bias = biasF[col];
#pragma unroll
            for (int r = 0; r < 4; ++r) {
                int row = rbase + r;
                if (row < n_nodes) {
                    float val = acc[ms][ni][r] + bias;
                    if (region == 0) {
                        qs[(size_t)row * 256 + col] = f2bf(val);
                    } else if (region == 1) {
                        int p8 = __builtin_amdgcn_cvt_pk_fp8_f32(val, val, 0, false);
                        kv[(size_t)row * 512 + (col - 256)] = (unsigned char)(p8 & 0xff);
                    } else {
                        sk[(size_t)row * 256 + (col - 768)] = f2bf(val);
                    }
                }
            }
        }
    }
}

// ---------------- fused edge aggregation + epilogue: 1 wave = 1 node ----------------
// 2x unrolled edge loop: each 32-lane half keeps 2 kv gathers in flight.
__global__ __launch_bounds__(256) void edge_agg_kernel(
    const int* __restrict__ row_ptr, const unsigned short* __restrict__ csr_src,
    const unsigned short* __restrict__ qs, const unsigned char* __restrict__ kv,
    const unsigned short* __restrict__ sk, const unsigned short* __restrict__ xb,
    const float* __restrict__ gamma, const float* __restrict__ beta,
    float* __restrict__ out) {
    int wv = threadIdx.x >> 6;
    int i = blockIdx.x * 4 + wv;          // 12500*4 = 50000 exact
    int lane = threadIdx.x & 63;
    int half = lane >> 5, l = lane & 31;

    // q channels l*8..+7, prescaled by log2(e)/sqrt(32)/64 (K stored x64)
    const float QS = 0.17677669529663687f * 1.4426950408889634f / 64.0f;
    uint4 qu = *reinterpret_cast<const uint4*>(qs + (size_t)i * 256 + l * 8);
    f32x2 qsc = {QS, QS};
    f32x2 q01 = bfpair(qu.x) * qsc;
    f32x2 q23 = bfpair(qu.y) * qsc;
    f32x2 q45 = bfpair(qu.z) * qsc;
    f32x2 q67 = bfpair(qu.w) * qsc;

    int e0 = row_ptr[i], e1 = row_ptr[i + 1];
    f32x2 acc0 = {0.f, 0.f}, acc1 = {0.f, 0.f}, acc2 = {0.f, 0.f}, acc3 = {0.f, 0.f};
    float den = 0.f;

#define EDGE_PROC(U)                                                     \
    {                                                                    \
        f32x2 k01 = __builtin_amdgcn_cvt_pk_f32_fp8(U.x, false);         \
        f32x2 v01 = __builtin_amdgcn_cvt_pk_f32_fp8(U.x, true);          \
        f32x2 k23 = __builtin_amdgcn_cvt_pk_f32_fp8(U.y, false);         \
        f32x2 v23 = __builtin_amdgcn_cvt_pk_f32_fp8(U.y, true);          \
        f32x2 k45 = __builtin_amdgcn_cvt_pk_f32_fp8(U.z, false);         \
        f32x2 v45 = __builtin_amdgcn_cvt_pk_f32_fp8(U.z, true);          \
        f32x2 k67 = __builtin_amdgcn_cvt_pk_f32_fp8(U.w, false);         \
        f32x2 v67 = __builtin_amdgcn_cvt_pk_f32_fp8(U.w, true);          \
        f32x2 d = q01 * k01;                                             \
        d = __builtin_elementwise_fma(q23, k23, d);                      \
        d = __builtin_elementwise_fma(q45, k45, d);                      \
        d = __builtin_elementwise_fma(q67, k67, d);                      \
        float s = d[0] + d[1];                                           \
        s += __shfl_xor(s, 1);                                           \
        s += __shfl_xor(s, 2);                                           \
        float w = exp2f(s);                                              \
        den += w;                                                        \
        f32x2 w2 = {w, w};                                               \
        acc0 = __builtin_elementwise_fma(w2, v01, acc0);                 \
        acc1 = __builtin_elementwise_fma(w2, v23, acc1);                 \
        acc2 = __builtin_elementwise_fma(w2, v45, acc2);                 \
        acc3 = __builtin_elementwise_fma(w2, v67, acc3);                 \
    }

    int e = e0 + half;
    int j0 = (e < e1) ? (int)csr_src[e] : 0;
    int j1 = (e + 2 < e1) ? (int)csr_src[e + 2] : 0;
    while (e + 2 < e1) {
        uint4 ua = *reinterpret_cast<const uint4*>(
            kv + (size_t)j0 * 512u + (unsigned)l * 16u);
        uint4 ub = *reinterpret_cast<const uint4*>(
            kv + (size_t)j1 * 512u + (unsigned)l * 16u);
        int jn0 = (e + 4 < e1) ? (int)csr_src[e + 4] : 0;
        int jn1 = (e + 6 < e1) ? (int)csr_src[e + 6] : 0;
        EDGE_PROC(ua)
        EDGE_PROC(ub)
        j0 = jn0;
        j1 = jn1;
        e += 4;
    }
    if (e < e1) {
        uint4 ua = *reinterpret_cast<const uint4*>(
            kv + (size_t)j0 * 512u + (unsigned)l * 16u);
        EDGE_PROC(ua)
    }
#undef EDGE_PROC

    // combine the two edge-halves (channels identical across halves)
    acc0[0] += __shfl_xor(acc0[0], 32); acc0[1] += __shfl_xor(acc0[1], 32);
    acc1[0] += __shfl_xor(acc1[0], 32); acc1[1] += __shfl_xor(acc1[1], 32);
    acc2[0] += __shfl_xor(acc2[0], 32); acc2[1] += __shfl_xor(acc2[1], 32);
    acc3[0] += __shfl_xor(acc3[0], 32); acc3[1] += __shfl_xor(acc3[1], 32);
    den += __shfl_xor(den, 32);
    float inv = (den > 0.f) ? 1.0f / (den * 64.0f) : 0.f;  // undo V x64

    // epilogue: skip + tanh-GELU (sigmoid form) + residual, per-lane 8 channels
    uint4 su = *reinterpret_cast<const uint4*>(sk + (size_t)i * 256 + l * 8);
    uint4 xu = *reinterpret_cast<const uint4*>(xb + (size_t)i * 256 + l * 8);
    const float C1 = -2.3022650556f;          // -2*log2(e)*0.7978845608
    const float C2 = -0.10294578f;            // C1*0.044715
    float s1 = 0.f, s2 = 0.f;
    f32x2 y01, y23, y45, y67;
#define GNN_PROC(A, SRAW, XRAW, Y)                                   \
    {                                                                \
        f32x2 skp = bfpair(SRAW), xr = bfpair(XRAW);                 \
        _Pragma("unroll")                                            \
        for (int qq = 0; qq < 2; ++qq) {                             \
            float pre = fmaf(A[qq], inv, skp[qq]);                   \
            float x2 = pre * pre;                                    \
            float arg = pre * fmaf(C2, x2, C1);                      \
            float gel = pre / (1.f + exp2f(arg));                    \
            float yy = xr[qq] + gel;                                 \
            Y[qq] = yy;                                              \
            s1 += yy;                                                \
            s2 = fmaf(yy, yy, s2);                                   \
        }                                                            \
    }
    GNN_PROC(acc0, su.x, xu.x, y01)
    GNN_PROC(acc1, su.y, xu.y, y23)
    GNN_PROC(acc2, su.z, xu.z, y45)
    GNN_PROC(acc3, su.w, xu.w, y67)
#undef GNN_PROC

    // LN reduce: each 32-lane half covers all 256 channels -> xor 1..16 suffices
#pragma unroll
    for (int m = 1; m <= 16; m <<= 1) {
        s1 += __shfl_xor(s1, m);
        s2 += __shfl_xor(s2, m);
    }
    float mu = s1 * (1.f / 256.f);
    float var = s2 * (1.f / 256.f) - mu * mu;
    float rstd = rsqrtf(var + 1e-5f);

    if (half == 0) {
        const float4* g4 = reinterpret_cast<const float4*>(gamma) + l * 2;
        const float4* b4 = reinterpret_cast<const float4*>(beta) + l * 2;
        float4 ga = g4[0], gb = g4[1], ba = b4[0], bb = b4[1];
        float4 o0, o1;
        o0.x = (y01[0] - mu) * rstd * ga.x + ba.x;
        o0.y = (y01[1] - mu) * rstd * ga.y + ba.y;
        o0.z = (y23[0] - mu) * rstd * ga.z + ba.z;
        o0.w = (y23[1] - mu) * rstd * ga.w + ba.w;
        o1.x = (y45[0] - mu) * rstd * gb.x + bb.x;
        o1.y = (y45[1] - mu) * rstd * gb.y + bb.y;
        o1.z = (y67[0] - mu) * rstd * gb.z + bb.z;
        o1.w = (y67[1] - mu) * rstd * gb.w + bb.w;
        float4* op = reinterpret_cast<float4*>(out + (size_t)i * 256 + l * 8);
        op[0] = o0;
        op[1] = o1;
    }
}

extern "C" void kernel_launch(void* const* d_in, const int* in_sizes, int n_in,
                              void* d_out, int out_size, void* d_ws, size_t ws_size,
                              hipStream_t stream) {
    const float* x    = (const float*)d_in[0];
    const int*   ei   = (const int*)d_in[1];
    const float* Wq   = (const float*)d_in[2];
    const float* bq   = (const float*)d_in[3];
    const float* Wk   = (const float*)d_in[4];
    const float* bk   = (const float*)d_in[5];
    const float* Wv   = (const float*)d_in[6];
    const float* bv   = (const float*)d_in[7];
    const float* Wsk  = (const float*)d_in[8];
    const float* bsk  = (const float*)d_in[9];
    const float* gamma = (const float*)d_in[10];
    const float* beta  = (const float*)d_in[11];
    const int* src = ei;
    const int* dst = ei + N_EDGES;

    char* ws = (char*)d_ws;
    size_t off = 0;
    auto alloc = [&](size_t bytes) -> void* {
        void* p = ws + off;
        off += (bytes + 255) & ~(size_t)255;
        return p;
    };
    unsigned short* xb     = (unsigned short*)alloc((size_t)N_NODES * 256 * 2);
    unsigned short* qs     = (unsigned short*)alloc((size_t)N_NODES * 256 * 2);
    unsigned char*  kvb    = (unsigned char*)alloc((size_t)N_NODES * 512);
    unsigned short* sk     = (unsigned short*)alloc((size_t)N_NODES * 256 * 2);
    unsigned short* wpack  = (unsigned short*)alloc(262144 * 2);
    float*          biasF  = (float*)alloc(1024 * 4);
    int*            deg    = (int*)alloc((size_t)N_NODES * 4);
    int*            rowp   = (int*)alloc((size_t)(N_NODES + 1) * 4);
    int*            fill   = (int*)alloc((size_t)N_NODES * 4);
    unsigned short* csr    = (unsigned short*)alloc((size_t)N_EDGES * 2);
    int*            btot   = (int*)alloc(64 * 4);
    (void)ws_size;

    hipMemsetAsync(deg, 0, (size_t)N_NODES * 4, stream);
    prep_kernel<<<10399, 256, 0, stream>>>(x, xb, dst, deg, Wq, Wk, Wv, Wsk,
                                           bq, bk, bv, bsk, wpack, biasF);
    scan1_kernel<<<50, 1024, 0, stream>>>(deg, rowp, btot, N_NODES);
    fixup_kernel<<<196, 256, 0, stream>>>(rowp, fill, btot, N_NODES);
    gemm_scatter_kernel<<<6272, 256, 0, stream>>>(src, dst, fill, csr,
                                                  xb, wpack, biasF, qs, kvb, sk, N_NODES);
    edge_agg_kernel<<<12500, 256, 0, stream>>>(rowp, csr, qs, kvb, sk, xb, gamma, beta,
                                               (float*)d_out);
}

// Round 15
// 218.484 us; speedup vs baseline: 1.3570x; 1.3570x over previous
//
#include <hip/hip_runtime.h>

#define N_NODES 50000
#define HID 256
#define HEADS 8
#define HDIM 32
#define N_EDGES 800000

typedef __bf16 bf16x8 __attribute__((ext_vector_type(8)));
typedef float f32x4 __attribute__((ext_vector_type(4)));
typedef float f32x2 __attribute__((ext_vector_type(2)));

__device__ __forceinline__ unsigned short f2bf(float f) {
    unsigned int b = __float_as_uint(f);
    unsigned int r = (b + 0x7FFFu + ((b >> 16) & 1u)) >> 16;
    return (unsigned short)r;
}
__device__ __forceinline__ float bf2f(unsigned short u) {
    return __uint_as_float(((unsigned int)u) << 16);
}
__device__ __forceinline__ f32x2 bfpair(unsigned int u) {
    f32x2 r;
    r[0] = __uint_as_float(u << 16);
    r[1] = __uint_as_float(u & 0xffff0000u);
    return r;
}

// Fused column p in [0,1024):
//   p<256      : Q col p (bf16 out)
//   256<=p<768 : p'=p-256; quad=p'>>2, r=p'&3: r<2 -> K ch quad*2+r,
//                r>=2 -> V ch quad*2+(r-2); scaled x64 (fp8 out, kkvv quads)
//   p>=768     : skip col p-768 (bf16 out)
__device__ __forceinline__ void fused_col_map(int p, int& mat, int& col, float& scale) {
    if (p < 256) { mat = 0; col = p; scale = 1.0f; }
    else if (p < 768) {
        int pp = p - 256;
        mat = ((pp & 2) ? 2 : 1);
        col = ((pp >> 2) << 1) | (pp & 1);
        scale = 64.0f;
    } else { mat = 3; col = p - 768; scale = 1.0f; }
}

// ---------------- fused: x fp32->bf16 | degree hist | weight pack ----------------
__global__ __launch_bounds__(256) void prep_kernel(
    const float* __restrict__ x, unsigned short* __restrict__ xb,
    const int* __restrict__ dst, int* __restrict__ deg,
    const float* __restrict__ Wq, const float* __restrict__ Wk,
    const float* __restrict__ Wv, const float* __restrict__ Ws,
    const float* __restrict__ bq, const float* __restrict__ bk,
    const float* __restrict__ bv, const float* __restrict__ bs,
    unsigned short* __restrict__ wpack, float* __restrict__ biasF) {
    int b = blockIdx.x;
    if (b < 6250) {
        int t = b * 256 + threadIdx.x;
        const float4* p = reinterpret_cast<const float4*>(x) + (size_t)t * 2;
        float4 f0 = p[0], f1 = p[1];
        uint4 o;
        o.x = (unsigned)f2bf(f0.x) | ((unsigned)f2bf(f0.y) << 16);
        o.y = (unsigned)f2bf(f0.z) | ((unsigned)f2bf(f0.w) << 16);
        o.z = (unsigned)f2bf(f1.x) | ((unsigned)f2bf(f1.y) << 16);
        o.w = (unsigned)f2bf(f1.z) | ((unsigned)f2bf(f1.w) << 16);
        reinterpret_cast<uint4*>(xb)[t] = o;
    } else if (b < 9375) {
        int e = (b - 6250) * 256 + threadIdx.x;
        atomicAdd(&deg[dst[e]], 1);
    } else {
        int t = (b - 9375) * 256 + threadIdx.x;  // 262144 total
        int e = t & 7, lane = (t >> 3) & 63, kk = (t >> 9) & 7, n_tile = t >> 12;
        int k = kk * 32 + (lane >> 4) * 8 + e;
        int p = n_tile * 16 + (lane & 15);
        const float* W[4] = {Wq, Wk, Wv, Ws};
        int mat, col; float scale;
        fused_col_map(p, mat, col, scale);
        wpack[t] = f2bf(W[mat][k * 256 + col] * scale);
        if (t < 1024) {
            const float* B[4] = {bq, bk, bv, bs};
            int mat2, col2; float s2;
            fused_col_map(t, mat2, col2, s2);
            biasF[t] = B[mat2][col2] * s2;
        }
    }
}

// ---------------- CSR build: parallel scan ----------------
__global__ __launch_bounds__(1024) void scan1_kernel(
    const int* __restrict__ deg, int* __restrict__ row_ptr,
    int* __restrict__ btot, int n) {
    int tid = threadIdx.x, lane = tid & 63, wv = tid >> 6;
    int idx = blockIdx.x * 1024 + tid;
    int v = (idx < n) ? deg[idx] : 0;
    int inc = v;
#pragma unroll
    for (int off = 1; off < 64; off <<= 1) {
        int t2 = __shfl_up(inc, off);
        if (lane >= off) inc += t2;
    }
    __shared__ int sW[16], sO[16];
    if (lane == 63) sW[wv] = inc;
    __syncthreads();
    if (tid < 16) {
        int vv = sW[tid], in2 = vv;
        for (int off = 1; off < 16; off <<= 1) {
            int t2 = __shfl_up(in2, off);
            if (tid >= off) in2 += t2;
        }
        sO[tid] = in2 - vv;
    }
    __syncthreads();
    int excl = sO[wv] + inc - v;
    if (idx <= n) row_ptr[idx] = excl;  // provisional
    if (tid == 1023) btot[blockIdx.x] = excl + v;
}

// fixup with inline 50-entry second-level scan
__global__ __launch_bounds__(256) void fixup_kernel(
    int* __restrict__ row_ptr, int* __restrict__ fill,
    const int* __restrict__ btot, int n) {
    __shared__ int sB;
    int tid = threadIdx.x;
    if (tid < 64) {
        int v = (tid < 50) ? btot[tid] : 0;
        int inc = v;
#pragma unroll
        for (int off = 1; off < 64; off <<= 1) {
            int t2 = __shfl_up(inc, off);
            if (tid >= off) inc += t2;
        }
        if (tid == (blockIdx.x >> 2)) sB = inc - v;
    }
    __syncthreads();
    int idx = blockIdx.x * 256 + tid;
    if (idx > n) return;
    int v = row_ptr[idx] + sB;
    row_ptr[idx] = v;
    if (idx < n) fill[idx] = v;
}

// ---------------- fused QKVS GEMM (LDS B-staging) + INTERLEAVED scatter ----------
// R13-exact (107us verified). Grid 9384 = 3128 triples. bid%3==2 -> scatter
// block bid/3 (3125 active); else GEMM block 2*(bid/3)+bid%3 (bijective
// 0..6255, 128 rows x 64 cols, 48 VGPR, ~40% occupancy). Interleaving keeps
// scatter co-resident with GEMM for the whole dispatch. R14's 256-row tile
// regressed (72 VGPR -> 19% occupancy): occupancy dominates this GEMM.
__global__ __launch_bounds__(256) void gemm_scatter_kernel(
    const int* __restrict__ src, const int* __restrict__ dst,
    int* __restrict__ fill, unsigned short* __restrict__ csr_src,
    const unsigned short* __restrict__ xb,     // [N][256] bf16
    const unsigned short* __restrict__ wpack,  // packed W (512 KB)
    const float* __restrict__ biasF,           // [1024]
    unsigned short* __restrict__ qs,           // [N][256] bf16
    unsigned char* __restrict__ kv,            // [N][512] fp8
    unsigned short* __restrict__ sk,           // [N][256] bf16
    int n_nodes) {
    __shared__ __align__(16) uint4 bsh[2048];  // 32 KB B slice
    int bidr = blockIdx.x;                     // 9384 = 3128 * 3
    int q3 = bidr / 3;
    int r3 = bidr - q3 * 3;
    if (r3 == 2) {
        // scatter block q3: 3125 active (q3 >= 3125 idle)
        int e = q3 * 256 + threadIdx.x;
        if (q3 < 3125 && e < N_EDGES) {
            int pos = atomicAdd(&fill[dst[e]], 1);
            csr_src[pos] = (unsigned short)src[e];
        }
        return;
    }
    int gid = q3 * 2 + r3;                     // 0..6255 bijective
    int work = (gid & 7) * 782 + (gid >> 3);   // XCD-chunked
    int mt = work >> 4;
    int nt = work & 15;
    int lane = threadIdx.x & 63;
    int wv = threadIdx.x >> 6;
    int row_w = mt * 128 + wv * 32;
    int n0 = nt * 64;
    int ntile0 = n0 >> 4;

    // stage B slice: contiguous 2048 uint4 starting at ntile0*8*64
    {
        const uint4* bsrc = reinterpret_cast<const uint4*>(wpack) +
                            (size_t)ntile0 * 8 * 64;
        int tid = threadIdx.x;
#pragma unroll
        for (int i = 0; i < 8; ++i)
            bsh[i * 256 + tid] = bsrc[i * 256 + tid];
    }
    __syncthreads();

    f32x4 acc[2][4];
#pragma unroll
    for (int mi = 0; mi < 2; ++mi)
#pragma unroll
        for (int ni = 0; ni < 4; ++ni) {
            f32x4 z = {0.f, 0.f, 0.f, 0.f};
            acc[mi][ni] = z;
        }

    int arow0 = min(row_w + (lane & 15), n_nodes - 1);
    int arow1 = min(row_w + 16 + (lane & 15), n_nodes - 1);
    int acol = (lane >> 4) * 8;

#pragma unroll
    for (int kk = 0; kk < 8; ++kk) {
        bf16x8 a[2], bfr[4];
        {
            uint4 u0 = *reinterpret_cast<const uint4*>(xb + (size_t)arow0 * 256 + kk * 32 + acol);
            uint4 u1 = *reinterpret_cast<const uint4*>(xb + (size_t)arow1 * 256 + kk * 32 + acol);
            a[0] = __builtin_bit_cast(bf16x8, u0);
            a[1] = __builtin_bit_cast(bf16x8, u1);
        }
#pragma unroll
        for (int ni = 0; ni < 4; ++ni) {
            uint4 u = bsh[(ni * 8 + kk) * 64 + lane];
            bfr[ni] = __builtin_bit_cast(bf16x8, u);
        }
#pragma unroll
        for (int mi = 0; mi < 2; ++mi)
#pragma unroll
            for (int ni = 0; ni < 4; ++ni)
                acc[mi][ni] = __builtin_amdgcn_mfma_f32_16x16x32_bf16(
                    a[mi], bfr[ni], acc[mi][ni], 0, 0, 0);
    }

    // epilogue: col = n0+ni*16+(lane&15), row = row_w+mi*16+(lane>>4)*4+r
    int region = (n0 < 256) ? 0 : (n0 < 768 ? 1 : 2);
#pragma unroll
    for (int mi = 0; mi < 2; ++mi) {
        int rbase = row_w + mi * 16 + (lane >> 4) * 4;
#pragma unroll
        for (int ni = 0; ni < 4; ++ni) {
            int col = n0 + ni * 16 + (lane & 15);
            float bias = biasF[col];
#pragma unroll
            for (int r = 0; r < 4; ++r) {
                int row = rbase + r;
                if (row < n_nodes) {
                    float val = acc[mi][ni][r] + bias;
                    if (region == 0) {
                        qs[(size_t)row * 256 + col] = f2bf(val);
                    } else if (region == 1) {
                        int p8 = __builtin_amdgcn_cvt_pk_fp8_f32(val, val, 0, false);
                        kv[(size_t)row * 512 + (col - 256)] = (unsigned char)(p8 & 0xff);
                    } else {
                        sk[(size_t)row * 256 + (col - 768)] = f2bf(val);
                    }
                }
            }
        }
    }
}

// ---------------- fused edge aggregation + epilogue: 1 wave = 1 node ----------------
// 2x unrolled edge loop: each 32-lane half keeps 2 kv gathers in flight.
__global__ __launch_bounds__(256) void edge_agg_kernel(
    const int* __restrict__ row_ptr, const unsigned short* __restrict__ csr_src,
    const unsigned short* __restrict__ qs, const unsigned char* __restrict__ kv,
    const unsigned short* __restrict__ sk, const unsigned short* __restrict__ xb,
    const float* __restrict__ gamma, const float* __restrict__ beta,
    float* __restrict__ out) {
    int wv = threadIdx.x >> 6;
    int i = blockIdx.x * 4 + wv;          // 12500*4 = 50000 exact
    int lane = threadIdx.x & 63;
    int half = lane >> 5, l = lane & 31;

    // q channels l*8..+7, prescaled by log2(e)/sqrt(32)/64 (K stored x64)
    const float QS = 0.17677669529663687f * 1.4426950408889634f / 64.0f;
    uint4 qu = *reinterpret_cast<const uint4*>(qs + (size_t)i * 256 + l * 8);
    f32x2 qsc = {QS, QS};
    f32x2 q01 = bfpair(qu.x) * qsc;
    f32x2 q23 = bfpair(qu.y) * qsc;
    f32x2 q45 = bfpair(qu.z) * qsc;
    f32x2 q67 = bfpair(qu.w) * qsc;

    int e0 = row_ptr[i], e1 = row_ptr[i + 1];
    f32x2 acc0 = {0.f, 0.f}, acc1 = {0.f, 0.f}, acc2 = {0.f, 0.f}, acc3 = {0.f, 0.f};
    float den = 0.f;

#define EDGE_PROC(U)                                                     \
    {                                                                    \
        f32x2 k01 = __builtin_amdgcn_cvt_pk_f32_fp8(U.x, false);         \
        f32x2 v01 = __builtin_amdgcn_cvt_pk_f32_fp8(U.x, true);          \
        f32x2 k23 = __builtin_amdgcn_cvt_pk_f32_fp8(U.y, false);         \
        f32x2 v23 = __builtin_amdgcn_cvt_pk_f32_fp8(U.y, true);          \
        f32x2 k45 = __builtin_amdgcn_cvt_pk_f32_fp8(U.z, false);         \
        f32x2 v45 = __builtin_amdgcn_cvt_pk_f32_fp8(U.z, true);          \
        f32x2 k67 = __builtin_amdgcn_cvt_pk_f32_fp8(U.w, false);         \
        f32x2 v67 = __builtin_amdgcn_cvt_pk_f32_fp8(U.w, true);          \
        f32x2 d = q01 * k01;                                             \
        d = __builtin_elementwise_fma(q23, k23, d);                      \
        d = __builtin_elementwise_fma(q45, k45, d);                      \
        d = __builtin_elementwise_fma(q67, k67, d);                      \
        float s = d[0] + d[1];                                           \
        s += __shfl_xor(s, 1);                                           \
        s += __shfl_xor(s, 2);                                           \
        float w = exp2f(s);                                              \
        den += w;                                                        \
        f32x2 w2 = {w, w};                                               \
        acc0 = __builtin_elementwise_fma(w2, v01, acc0);                 \
        acc1 = __builtin_elementwise_fma(w2, v23, acc1);                 \
        acc2 = __builtin_elementwise_fma(w2, v45, acc2);                 \
        acc3 = __builtin_elementwise_fma(w2, v67, acc3);                 \
    }

    int e = e0 + half;
    int j0 = (e < e1) ? (int)csr_src[e] : 0;
    int j1 = (e + 2 < e1) ? (int)csr_src[e + 2] : 0;
    while (e + 2 < e1) {
        uint4 ua = *reinterpret_cast<const uint4*>(
            kv + (size_t)j0 * 512u + (unsigned)l * 16u);
        uint4 ub = *reinterpret_cast<const uint4*>(
            kv + (size_t)j1 * 512u + (unsigned)l * 16u);
        int jn0 = (e + 4 < e1) ? (int)csr_src[e + 4] : 0;
        int jn1 = (e + 6 < e1) ? (int)csr_src[e + 6] : 0;
        EDGE_PROC(ua)
        EDGE_PROC(ub)
        j0 = jn0;
        j1 = jn1;
        e += 4;
    }
    if (e < e1) {
        uint4 ua = *reinterpret_cast<const uint4*>(
            kv + (size_t)j0 * 512u + (unsigned)l * 16u);
        EDGE_PROC(ua)
    }
#undef EDGE_PROC

    // combine the two edge-halves (channels identical across halves)
    acc0[0] += __shfl_xor(acc0[0], 32); acc0[1] += __shfl_xor(acc0[1], 32);
    acc1[0] += __shfl_xor(acc1[0], 32); acc1[1] += __shfl_xor(acc1[1], 32);
    acc2[0] += __shfl_xor(acc2[0], 32); acc2[1] += __shfl_xor(acc2[1], 32);
    acc3[0] += __shfl_xor(acc3[0], 32); acc3[1] += __shfl_xor(acc3[1], 32);
    den += __shfl_xor(den, 32);
    float inv = (den > 0.f) ? 1.0f / (den * 64.0f) : 0.f;  // undo V x64

    // epilogue: skip + tanh-GELU (sigmoid form) + residual, per-lane 8 channels
    uint4 su = *reinterpret_cast<const uint4*>(sk + (size_t)i * 256 + l * 8);
    uint4 xu = *reinterpret_cast<const uint4*>(xb + (size_t)i * 256 + l * 8);
    const float C1 = -2.3022650556f;          // -2*log2(e)*0.7978845608
    const float C2 = -0.10294578f;            // C1*0.044715
    float s1 = 0.f, s2 = 0.f;
    f32x2 y01, y23, y45, y67;
#define GNN_PROC(A, SRAW, XRAW, Y)                                   \
    {                                                                \
        f32x2 skp = bfpair(SRAW), xr = bfpair(XRAW);                 \
        _Pragma("unroll")                                            \
        for (int qq = 0; qq < 2; ++qq) {                             \
            float pre = fmaf(A[qq], inv, skp[qq]);                   \
            float x2 = pre * pre;                                    \
            float arg = pre * fmaf(C2, x2, C1);                      \
            float gel = pre / (1.f + exp2f(arg));                    \
            float yy = xr[qq] + gel;                                 \
            Y[qq] = yy;                                              \
            s1 += yy;                                                \
            s2 = fmaf(yy, yy, s2);                                   \
        }                                                            \
    }
    GNN_PROC(acc0, su.x, xu.x, y01)
    GNN_PROC(acc1, su.y, xu.y, y23)
    GNN_PROC(acc2, su.z, xu.z, y45)
    GNN_PROC(acc3, su.w, xu.w, y67)
#undef GNN_PROC

    // LN reduce: each 32-lane half covers all 256 channels -> xor 1..16 suffices
#pragma unroll
    for (int m = 1; m <= 16; m <<= 1) {
        s1 += __shfl_xor(s1, m);
        s2 += __shfl_xor(s2, m);
    }
    float mu = s1 * (1.f / 256.f);
    float var = s2 * (1.f / 256.f) - mu * mu;
    float rstd = rsqrtf(var + 1e-5f);

    if (half == 0) {
        const float4* g4 = reinterpret_cast<const float4*>(gamma) + l * 2;
        const float4* b4 = reinterpret_cast<const float4*>(beta) + l * 2;
        float4 ga = g4[0], gb = g4[1], ba = b4[0], bb = b4[1];
        float4 o0, o1;
        o0.x = (y01[0] - mu) * rstd * ga.x + ba.x;
        o0.y = (y01[1] - mu) * rstd * ga.y + ba.y;
        o0.z = (y23[0] - mu) * rstd * ga.z + ba.z;
        o0.w = (y23[1] - mu) * rstd * ga.w + ba.w;
        o1.x = (y45[0] - mu) * rstd * gb.x + bb.x;
        o1.y = (y45[1] - mu) * rstd * gb.y + bb.y;
        o1.z = (y67[0] - mu) * rstd * gb.z + bb.z;
        o1.w = (y67[1] - mu) * rstd * gb.w + bb.w;
        float4* op = reinterpret_cast<float4*>(out + (size_t)i * 256 + l * 8);
        op[0] = o0;
        op[1] = o1;
    }
}

extern "C" void kernel_launch(void* const* d_in, const int* in_sizes, int n_in,
                              void* d_out, int out_size, void* d_ws, size_t ws_size,
                              hipStream_t stream) {
    const float* x    = (const float*)d_in[0];
    const int*   ei   = (const int*)d_in[1];
    const float* Wq   = (const float*)d_in[2];
    const float* bq   = (const float*)d_in[3];
    const float* Wk   = (const float*)d_in[4];
    const float* bk   = (const float*)d_in[5];
    const float* Wv   = (const float*)d_in[6];
    const float* bv   = (const float*)d_in[7];
    const float* Wsk  = (const float*)d_in[8];
    const float* bsk  = (const float*)d_in[9];
    const float* gamma = (const float*)d_in[10];
    const float* beta  = (const float*)d_in[11];
    const int* src = ei;
    const int* dst = ei + N_EDGES;

    char* ws = (char*)d_ws;
    size_t off = 0;
    auto alloc = [&](size_t bytes) -> void* {
        void* p = ws + off;
        off += (bytes + 255) & ~(size_t)255;
        return p;
    };
    unsigned short* xb     = (unsigned short*)alloc((size_t)N_NODES * 256 * 2);
    unsigned short* qs     = (unsigned short*)alloc((size_t)N_NODES * 256 * 2);
    unsigned char*  kvb    = (unsigned char*)alloc((size_t)N_NODES * 512);
    unsigned short* sk     = (unsigned short*)alloc((size_t)N_NODES * 256 * 2);
    unsigned short* wpack  = (unsigned short*)alloc(262144 * 2);
    float*          biasF  = (float*)alloc(1024 * 4);
    int*            deg    = (int*)alloc((size_t)N_NODES * 4);
    int*            rowp   = (int*)alloc((size_t)(N_NODES + 1) * 4);
    int*            fill   = (int*)alloc((size_t)N_NODES * 4);
    unsigned short* csr    = (unsigned short*)alloc((size_t)N_EDGES * 2);
    int*            btot   = (int*)alloc(64 * 4);
    (void)ws_size;

    hipMemsetAsync(deg, 0, (size_t)N_NODES * 4, stream);
    prep_kernel<<<10399, 256, 0, stream>>>(x, xb, dst, deg, Wq, Wk, Wv, Wsk,
                                           bq, bk, bv, bsk, wpack, biasF);
    scan1_kernel<<<50, 1024, 0, stream>>>(deg, rowp, btot, N_NODES);
    fixup_kernel<<<196, 256, 0, stream>>>(rowp, fill, btot, N_NODES);
    gemm_scatter_kernel<<<9384, 256, 0, stream>>>(src, dst, fill, csr,
                                                  xb, wpack, biasF, qs, kvb, sk, N_NODES);
    edge_agg_kernel<<<12500, 256, 0, stream>>>(rowp, csr, qs, kvb, sk, xb, gamma, beta,
                                               (float*)d_out);
}